// Round 1
// baseline (226.277 us; speedup 1.0000x reference)
//
#include <hip/hip_runtime.h>

// Problem constants (from setup_inputs): B=4, S=8, T=2048, R=256
#define T_N 2048
#define R_N 256
#define SLICES 32                     // B*S
#define NELEM (SLICES * T_N * R_N)    // 16,777,216 per tensor
#define INFV 3.0e38f
#define MIN_BLOCKS 2048               // 2048 x 256 threads, 8 float4/tensor/thread
#define MIN_THREADS (MIN_BLOCKS * 256)
#define LSTR 2056                     // list stride: 2048 + 8 sentinel slots

// Word-level XOR bank swizzle: logical e -> physical e ^ ((e>>5)&31).
// Kills the structural stride-8-float (bank {0,8,16,24}) aliasing of the
// merge/corank access pattern. Sentinels 2048..2055 map to themselves.
#define XS(e) ((e) ^ (((e) >> 5) & 31))

// Deep-ILP streaming min (unchanged: ~25us, HBM-bound).
__global__ __launch_bounds__(256) void kmin(const float* __restrict__ x,
                                            const float* __restrict__ y,
                                            float* __restrict__ partial,
                                            float* __restrict__ out) {
    if (blockIdx.x == 0 && threadIdx.x < 4) out[threadIdx.x] = 0.0f;
    const int g0 = blockIdx.x * 256 + threadIdx.x;   // 0..524287
    const float4* __restrict__ x4 = (const float4*)x;
    const float4* __restrict__ y4 = (const float4*)y;
    float m0 = INFV, m1 = INFV;
    #pragma unroll
    for (int half = 0; half < 2; ++half) {
        float4 va[4], vb[4];
        #pragma unroll
        for (int it = 0; it < 4; ++it) {
            const int idx = g0 + (half * 4 + it) * MIN_THREADS;
            va[it] = x4[idx];
            vb[it] = y4[idx];
        }
        #pragma unroll
        for (int it = 0; it < 4; ++it) {
            m0 = fminf(m0, fminf(fminf(va[it].x, va[it].y), fminf(va[it].z, va[it].w)));
            m1 = fminf(m1, fminf(fminf(vb[it].x, vb[it].y), fminf(vb[it].z, vb[it].w)));
        }
    }
    float m = fminf(m0, m1);
    #pragma unroll
    for (int off = 32; off; off >>= 1) m = fminf(m, __shfl_down(m, off));
    __shared__ float sm[4];
    if ((threadIdx.x & 63) == 0) sm[threadIdx.x >> 6] = m;
    __syncthreads();
    if (threadIdx.x == 0)
        partial[blockIdx.x] = fminf(fminf(sm[0], sm[1]), fminf(sm[2], sm[3]));
}

// 512-thread block = 2 problems, 4 waves/problem. LDS ~33KB -> 4 blocks/CU
// (vs 2 at 1024 threads): finer staging/compute interleave across blocks,
// 100% theoretical occupancy, cheaper 8-wave barriers. Per-problem scan /
// corank / merge arithmetic is IDENTICAL to the verified R6 structure.
__global__ __launch_bounds__(512, 8) void kmain(const float* __restrict__ x,
                                                const float* __restrict__ y,
                                                const float* __restrict__ partial,
                                                float* __restrict__ out) {
    __shared__ float L[4 * LSTR];     // problem p: U at (2p)*LSTR, V at (2p+1)*LSTR
    __shared__ float red8[8];
    __shared__ float psum[2][2][4];   // [problem][list][wave-chunk] scan partials
    __shared__ float pacc[2][4];      // [problem][wave] result partials

    const int tid = threadIdx.x;
    const int w = tid >> 6;           // wave 0..7
    const int lane = tid & 63;

    // ---- phase 0: global min (partial[2048], four elements per thread) ----
    {
        float m = fminf(fminf(partial[tid], partial[tid + 512]),
                        fminf(partial[tid + 1024], partial[tid + 1536]));
        #pragma unroll
        for (int off = 32; off; off >>= 1) m = fminf(m, __shfl_down(m, off));
        if (lane == 0) red8[w] = m;
    }
    __syncthreads();
    float mn = red8[0];
    #pragma unroll
    for (int k = 1; k < 8; ++k) mn = fminf(mn, red8[k]);
    const float sh = 1.1f * fminf(mn, 0.0f);

    // ---- XCD-aware remap: 8 blocks sharing a 64B global line -> same XCD ----
    // blk = xcd + 8*(sub + 8*((bs<<1)|e)); rp = (((e<<3)+xcd)<<3)|sub
    const int blk = blockIdx.x;
    const int xcd = blk & 7;
    const int k2 = blk >> 3;
    const int sub = k2 & 7;                         // 8 line-sharing siblings
    const int rest = k2 >> 3;
    const int rp = ((((rest & 1) << 3) + xcd) << 3) | sub;   // 0..127 r-pair
    const int bs = rest >> 1;                                // 0..31
    const size_t base = (size_t)bs * (T_N * R_N) + (size_t)(rp * 2);

    // ---- sentinels: logical 2048..2055 (swizzle-identity) = INF ----
    if (tid < 32) L[(tid >> 3) * LSTR + T_N + (tid & 7)] = INFV;

    // ---- staging: swizzled scalar writes (stride-1 pattern: 2/bank, free) ----
    #pragma unroll
    for (int it = 0; it < 4; ++it) {
        const int t = tid + 512 * it;
        const int ts = XS(t);
        const float2 a = *(const float2*)(x + base + (size_t)t * R_N);
        const float2 b = *(const float2*)(y + base + (size_t)t * R_N);
        L[0 * LSTR + ts] = a.x - sh;  L[2 * LSTR + ts] = a.y - sh;
        L[1 * LSTR + ts] = b.x - sh;  L[3 * LSTR + ts] = b.y - sh;
    }
    __syncthreads();

    const int p  = w >> 2;            // problem 0..1
    const int wl = w & 3;             // wave within problem
    const int pl = (wl << 6) | lane;  // problem-lane 0..255
    float* __restrict__ cu = &L[(2 * p) * LSTR];
    float* __restrict__ cv = &L[(2 * p + 1) * LSTR];

    // ---- scan: lane owns logical [8*pl, 8*pl+8), scalar swizzled access ----
    {
        int off8[8];
        #pragma unroll
        for (int k = 0; k < 8; ++k) off8[k] = XS(8 * pl + k);
        float uu[8], vv8[8];
        float su = 0.f, sv = 0.f;
        #pragma unroll
        for (int k = 0; k < 8; ++k) { uu[k] = cu[off8[k]]; su += uu[k]; }
        #pragma unroll
        for (int k = 0; k < 8; ++k) { vv8[k] = cv[off8[k]]; sv += vv8[k]; }
        float iu = su, iv = sv;
        #pragma unroll
        for (int off = 1; off < 64; off <<= 1) {
            const float a = __shfl_up(iu, off);
            const float b = __shfl_up(iv, off);
            if (lane >= off) { iu += a; iv += b; }
        }
        if (lane == 63) { psum[p][0][wl] = iu; psum[p][1][wl] = iv; }
        __syncthreads();
        float prefU = 0.f, totU = 0.f, prefV = 0.f, totV = 0.f;
        #pragma unroll
        for (int k = 0; k < 4; ++k) {
            const float a = psum[p][0][k], b = psum[p][1][k];
            totU += a; totV += b;
            if (k < wl) { prefU += a; prefV += b; }
        }
        const float invU = 1.0f / totU, invV = 1.0f / totV;
        float ru = prefU + (iu - su);
        float rv = prefV + (iv - sv);
        #pragma unroll
        for (int k = 0; k < 8; ++k) { ru += uu[k];  cu[off8[k]] = ru * invU; }
        #pragma unroll
        for (int k = 0; k < 8; ++k) { rv += vv8[k]; cv[off8[k]] = rv * invV; }
    }
    __syncthreads();

    // ---- co-rank partition: lane handles merged window [16*pl, 16*pl+16) ----
    const int d = pl << 4;
    int i = 0, j = 0;
    if (d > 0) {
        int lo = (d > T_N) ? (d - T_N) : 0;
        int hi = (d < T_N) ? d : T_N;
        while (lo < hi) {
            const int mid = (lo + hi) >> 1;
            if (cu[XS(mid)] <= cv[XS(d - mid - 1)]) lo = mid + 1; else hi = mid;
        }
        i = lo; j = d - lo;
    }
    float qprev = 0.0f;
    if (d > 0) {
        const float pa_ = (i > 0) ? cu[XS(i - 1)] : -INFV;
        const float pb_ = (j > 0) ? cv[XS(j - 1)] : -INFV;
        qprev = fmaxf(pa_, pb_);
    }

    // ---- merge: 16 steps, refill only the advanced list, sentinel-direct ----
    float uv = cu[XS(i)];
    float vv = cv[XS(j)];
    float acc = 0.0f;
    #pragma unroll
    for (int s = 0; s < 16; ++s) {
        const bool take = (uv <= vv);
        const float q = fminf(uv, vv);
        const float dd = (float)(min(i, T_N - 1) - min(j, T_N - 1));
        acc += (q - qprev) * dd * dd;
        qprev = q;
        i += take ? 1 : 0;
        j += take ? 0 : 1;
        if (s < 15) {
            const int ni = take ? i : j;           // advanced index (<= 2048)
            const float* bp = take ? cu : cv;
            const float r = bp[XS(ni)];
            uv = take ? r : uv;
            vv = take ? vv : r;
        }
    }

    // ---- reduce: wave -> LDS -> one atomic per block ----
    #pragma unroll
    for (int off = 32; off; off >>= 1) acc += __shfl_down(acc, off);
    if (lane == 0) pacc[p][wl] = acc;
    __syncthreads();
    if (tid == 0) {
        float r = 0.f;
        #pragma unroll
        for (int pp = 0; pp < 2; ++pp)
            r += (pacc[pp][0] + pacc[pp][1]) + (pacc[pp][2] + pacc[pp][3]);
        atomicAdd(&out[bs >> 3], r * (1.0f / ((float)T_N * (float)T_N)));
    }
}

extern "C" void kernel_launch(void* const* d_in, const int* in_sizes, int n_in,
                              void* d_out, int out_size, void* d_ws, size_t ws_size,
                              hipStream_t stream) {
    const float* x = (const float*)d_in[0];
    const float* y = (const float*)d_in[1];
    float* out = (float*)d_out;
    float* partial = (float*)d_ws;   // MIN_BLOCKS floats (8 KiB)

    kmin<<<MIN_BLOCKS, 256, 0, stream>>>(x, y, partial, out);
    kmain<<<SLICES * 128, 512, 0, stream>>>(x, y, partial, out);
}

// Round 2
// 198.414 us; speedup vs baseline: 1.1404x; 1.1404x over previous
//
#include <hip/hip_runtime.h>

// Problem constants (from setup_inputs): B=4, S=8, T=2048, R=256
#define T_N 2048
#define R_N 256
#define SLICES 32                     // B*S
#define NELEM (SLICES * T_N * R_N)    // 16,777,216 per tensor
#define INFV 3.0e38f
#define MIN_BLOCKS 2048               // 2048 x 256 threads, 8 float4/tensor/thread
#define MIN_THREADS (MIN_BLOCKS * 256)
#define LSTR 2056                     // list stride: 2048 + 8 sentinel slots

// Pair-preserving XOR bank swizzle: logical word e -> e ^ ((e>>4)&30).
// XORs bank bits [4:1] with bits [8:5]; bit 0 is preserved, so even/odd
// element pairs stay physically adjacent -> ds_read/write_b64 legal.
// Conflict-free for: stride-1 staging writes, stride-8-word scan pairs,
// and spreads the stride-8 corank/merge patterns. Sentinels 2048..2055
// map to themselves ((e>>4)&30 == 0 for 2048..2055? e>>4=128, &30=0 -> id).
#define XS(e) ((e) ^ (((e) >> 4) & 30))

// DPP wave-64 min-reduce step (min is order-insensitive -> bit-safe).
// old = +inf identity; bound_ctrl=false keeps old for out-of-row lanes.
#define DPPMIN(x, ctrl, rmask)                                                 \
    fminf((x), __int_as_float(__builtin_amdgcn_update_dpp(                     \
        0x7f800000, __float_as_int(x), (ctrl), (rmask), 0xf, false)))

// Deep-ILP streaming min (unchanged: ~25us, HBM-bound).
__global__ __launch_bounds__(256) void kmin(const float* __restrict__ x,
                                            const float* __restrict__ y,
                                            float* __restrict__ partial,
                                            float* __restrict__ out) {
    if (blockIdx.x == 0 && threadIdx.x < 4) out[threadIdx.x] = 0.0f;
    const int g0 = blockIdx.x * 256 + threadIdx.x;   // 0..524287
    const float4* __restrict__ x4 = (const float4*)x;
    const float4* __restrict__ y4 = (const float4*)y;
    float m0 = INFV, m1 = INFV;
    #pragma unroll
    for (int half = 0; half < 2; ++half) {
        float4 va[4], vb[4];
        #pragma unroll
        for (int it = 0; it < 4; ++it) {
            const int idx = g0 + (half * 4 + it) * MIN_THREADS;
            va[it] = x4[idx];
            vb[it] = y4[idx];
        }
        #pragma unroll
        for (int it = 0; it < 4; ++it) {
            m0 = fminf(m0, fminf(fminf(va[it].x, va[it].y), fminf(va[it].z, va[it].w)));
            m1 = fminf(m1, fminf(fminf(vb[it].x, vb[it].y), fminf(vb[it].z, vb[it].w)));
        }
    }
    float m = fminf(m0, m1);
    #pragma unroll
    for (int off = 32; off; off >>= 1) m = fminf(m, __shfl_down(m, off));
    __shared__ float sm[4];
    if ((threadIdx.x & 63) == 0) sm[threadIdx.x >> 6] = m;
    __syncthreads();
    if (threadIdx.x == 0)
        partial[blockIdx.x] = fminf(fminf(sm[0], sm[1]), fminf(sm[2], sm[3]));
}

// 1024-thread block = 4 problems, 4 waves/problem (verified R6 structure).
// This revision cuts LDS-pipe instructions ~27%: b64 staging (8 vs 16),
// b64 scan (16 vs 32), DPP phase-0 min (0 vs 6 ds_bpermute). All
// order-sensitive arithmetic (scan adds, merge, sums) is bit-identical.
__global__ __launch_bounds__(1024, 8) void kmain(const float* __restrict__ x,
                                                 const float* __restrict__ y,
                                                 const float* __restrict__ partial,
                                                 float* __restrict__ out) {
    __shared__ __align__(16) float L[8 * LSTR];  // problem p: U at (2p)*LSTR, V at (2p+1)*LSTR
    __shared__ float red16[16];
    __shared__ float psum[4][2][4];   // [problem][list][wave-chunk] scan partials
    __shared__ float pacc[4][4];      // [problem][wave] result partials

    const int tid = threadIdx.x;
    const int w = tid >> 6;           // wave 0..15
    const int lane = tid & 63;

    // ---- XCD-aware remap: 4 blocks sharing a 64B global line -> same XCD ----
    const int blk = blockIdx.x;
    const int xcd = blk & 7;
    const int k2 = blk >> 3;
    const int sub = k2 & 3;
    const int rest = k2 >> 2;
    const int rt = (((rest & 1) << 3) + xcd) * 4 + sub;   // 0..63
    const int bs = rest >> 1;                              // 0..31
    const size_t base = (size_t)bs * (T_N * R_N) + (size_t)(rt * 4);

    // ---- issue staging loads EARLY (independent of sh): rows 2tid, 2tid+1 ----
    const int r0 = tid << 1;
    const float4 a0 = *(const float4*)(x + base + (size_t)r0 * R_N);
    const float4 a1 = *(const float4*)(x + base + (size_t)(r0 + 1) * R_N);
    const float4 b0 = *(const float4*)(y + base + (size_t)r0 * R_N);
    const float4 b1 = *(const float4*)(y + base + (size_t)(r0 + 1) * R_N);

    // ---- phase 0: global min (partial[2048]) via DPP (no LDS-pipe shuffles) ----
    {
        float m = fminf(partial[tid], partial[tid + 1024]);
        m = DPPMIN(m, 0x111, 0xf);    // row_shr:1
        m = DPPMIN(m, 0x112, 0xf);    // row_shr:2
        m = DPPMIN(m, 0x114, 0xf);    // row_shr:4
        m = DPPMIN(m, 0x118, 0xf);    // row_shr:8
        m = DPPMIN(m, 0x142, 0xa);    // row_bcast:15 -> rows 1,3
        m = DPPMIN(m, 0x143, 0xc);    // row_bcast:31 -> rows 2,3
        if (lane == 63) red16[w] = m; // lane 63 holds the wave min
    }
    // ---- sentinels: logical 2048..2055 (swizzle-identity) = INF ----
    if (tid < 64) L[(tid >> 3) * LSTR + T_N + (tid & 7)] = INFV;
    __syncthreads();
    float mn = red16[0];
    #pragma unroll
    for (int k = 1; k < 16; ++k) mn = fminf(mn, red16[k]);
    const float sh = 1.1f * fminf(mn, 0.0f);

    // ---- staging: b64 swizzled pair writes (elements 2tid, 2tid+1) ----
    {
        const int ws_ = XS(r0);       // even -> 8B-aligned (list base 8224B mult)
        *(float2*)&L[0 * LSTR + ws_] = make_float2(a0.x - sh, a1.x - sh);
        *(float2*)&L[2 * LSTR + ws_] = make_float2(a0.y - sh, a1.y - sh);
        *(float2*)&L[4 * LSTR + ws_] = make_float2(a0.z - sh, a1.z - sh);
        *(float2*)&L[6 * LSTR + ws_] = make_float2(a0.w - sh, a1.w - sh);
        *(float2*)&L[1 * LSTR + ws_] = make_float2(b0.x - sh, b1.x - sh);
        *(float2*)&L[3 * LSTR + ws_] = make_float2(b0.y - sh, b1.y - sh);
        *(float2*)&L[5 * LSTR + ws_] = make_float2(b0.z - sh, b1.z - sh);
        *(float2*)&L[7 * LSTR + ws_] = make_float2(b0.w - sh, b1.w - sh);
    }
    __syncthreads();

    const int p  = w >> 2;            // problem 0..3
    const int wl = w & 3;             // wave within problem
    const int pl = (wl << 6) | lane;  // problem-lane 0..255
    float* __restrict__ cu = &L[(2 * p) * LSTR];
    float* __restrict__ cv = &L[(2 * p + 1) * LSTR];

    // ---- scan: lane owns logical [8*pl, 8*pl+8), b64 pair access ----
    {
        int offp[4];
        #pragma unroll
        for (int c = 0; c < 4; ++c) offp[c] = XS(8 * pl + 2 * c);
        float uu[8], vv8[8];
        float su = 0.f, sv = 0.f;
        #pragma unroll
        for (int c = 0; c < 4; ++c) {
            const float2 t2 = *(const float2*)&cu[offp[c]];
            uu[2 * c] = t2.x; uu[2 * c + 1] = t2.y;
        }
        #pragma unroll
        for (int k = 0; k < 8; ++k) su += uu[k];
        #pragma unroll
        for (int c = 0; c < 4; ++c) {
            const float2 t2 = *(const float2*)&cv[offp[c]];
            vv8[2 * c] = t2.x; vv8[2 * c + 1] = t2.y;
        }
        #pragma unroll
        for (int k = 0; k < 8; ++k) sv += vv8[k];
        float iu = su, iv = sv;
        #pragma unroll
        for (int off = 1; off < 64; off <<= 1) {
            const float a = __shfl_up(iu, off);
            const float b = __shfl_up(iv, off);
            if (lane >= off) { iu += a; iv += b; }
        }
        if (lane == 63) { psum[p][0][wl] = iu; psum[p][1][wl] = iv; }
        __syncthreads();
        float prefU = 0.f, totU = 0.f, prefV = 0.f, totV = 0.f;
        #pragma unroll
        for (int k = 0; k < 4; ++k) {
            const float a = psum[p][0][k], b = psum[p][1][k];
            totU += a; totV += b;
            if (k < wl) { prefU += a; prefV += b; }
        }
        const float invU = 1.0f / totU, invV = 1.0f / totV;
        float ru = prefU + (iu - su);
        float rv = prefV + (iv - sv);
        #pragma unroll
        for (int c = 0; c < 4; ++c) {
            const float ra = ru + uu[2 * c];
            const float rb = ra + uu[2 * c + 1];
            ru = rb;
            *(float2*)&cu[offp[c]] = make_float2(ra * invU, rb * invU);
        }
        #pragma unroll
        for (int c = 0; c < 4; ++c) {
            const float ra = rv + vv8[2 * c];
            const float rb = ra + vv8[2 * c + 1];
            rv = rb;
            *(float2*)&cv[offp[c]] = make_float2(ra * invV, rb * invV);
        }
    }
    __syncthreads();

    // ---- co-rank partition: lane handles merged window [16*pl, 16*pl+16) ----
    const int d = pl << 4;
    int i = 0, j = 0;
    if (d > 0) {
        int lo = (d > T_N) ? (d - T_N) : 0;
        int hi = (d < T_N) ? d : T_N;
        while (lo < hi) {
            const int mid = (lo + hi) >> 1;
            if (cu[XS(mid)] <= cv[XS(d - mid - 1)]) lo = mid + 1; else hi = mid;
        }
        i = lo; j = d - lo;
    }
    float qprev = 0.0f;
    if (d > 0) {
        const float pa_ = (i > 0) ? cu[XS(i - 1)] : -INFV;
        const float pb_ = (j > 0) ? cv[XS(j - 1)] : -INFV;
        qprev = fmaxf(pa_, pb_);
    }

    // ---- merge: 16 steps, refill only the advanced list, sentinel-direct ----
    float uv = cu[XS(i)];
    float vv = cv[XS(j)];
    float acc = 0.0f;
    #pragma unroll
    for (int s = 0; s < 16; ++s) {
        const bool take = (uv <= vv);
        const float q = fminf(uv, vv);
        const float dd = (float)(min(i, T_N - 1) - min(j, T_N - 1));
        acc += (q - qprev) * dd * dd;
        qprev = q;
        i += take ? 1 : 0;
        j += take ? 0 : 1;
        if (s < 15) {
            const int ni = take ? i : j;           // advanced index (<= 2048)
            const float* bp = take ? cu : cv;
            const float r = bp[XS(ni)];
            uv = take ? r : uv;
            vv = take ? vv : r;
        }
    }

    // ---- reduce: wave -> LDS -> one atomic per block (order preserved) ----
    #pragma unroll
    for (int off = 32; off; off >>= 1) acc += __shfl_down(acc, off);
    if (lane == 0) pacc[p][wl] = acc;
    __syncthreads();
    if (tid == 0) {
        float r = 0.f;
        #pragma unroll
        for (int pp = 0; pp < 4; ++pp)
            r += (pacc[pp][0] + pacc[pp][1]) + (pacc[pp][2] + pacc[pp][3]);
        atomicAdd(&out[bs >> 3], r * (1.0f / ((float)T_N * (float)T_N)));
    }
}

extern "C" void kernel_launch(void* const* d_in, const int* in_sizes, int n_in,
                              void* d_out, int out_size, void* d_ws, size_t ws_size,
                              hipStream_t stream) {
    const float* x = (const float*)d_in[0];
    const float* y = (const float*)d_in[1];
    float* out = (float*)d_out;
    float* partial = (float*)d_ws;   // MIN_BLOCKS floats (8 KiB)

    kmin<<<MIN_BLOCKS, 256, 0, stream>>>(x, y, partial, out);
    kmain<<<SLICES * 64, 1024, 0, stream>>>(x, y, partial, out);
}